// Round 12
// baseline (397.661 us; speedup 1.0000x reference)
//
#include <hip/hip_runtime.h>

#define BB 1024
#define TT 2048
#define NIN 8
#define NHI 64

#define CS 2.8853900817779268f      /* 2*log2(e) */
#define NL2E 1.4426950408889634f    /* log2(e) */
#define DELTA (40.94f / 2047.0f)

typedef float v2f __attribute__((ext_vector_type(2)));

__device__ __forceinline__ v2f vfma(v2f a, v2f b, v2f c) {
    return __builtin_elementwise_fma(a, b, c);
}

template<int CTRL>
__device__ __forceinline__ float qperm(float x) {
    int r = __builtin_amdgcn_mov_dpp(__float_as_int(x), CTRL, 0xF, 0xF, true);
    return __int_as_float(r);
}

// ---------------- precompute g = h*r records [b][s][{gg,ga,gc}] -------------
// (r11 verbatim — proven) Two batches (b, b+512) per thread as a float2 pair;
// weights via scalar pipe; shared-exp interiors; one rcp per 3 sigmoids.
__global__ __launch_bounds__(256) void precompute_r(
    const float* __restrict__ u, const float* __restrict__ Wni,
    const float* __restrict__ bni, const float* __restrict__ Wli,
    const float* __restrict__ bli, const float* __restrict__ tau,
    float* __restrict__ r3)
{
    int lt = threadIdx.x;
    int lane = lt & 63;
    int gw = blockIdx.x * 4 + (lt >> 6);        // 512*33 = 16896 waves
    int b = gw / 33;                            // 0..511
    int chunk = gw % 33;
    int s = chunk * 63 + lane;
    int sc = s < TT ? s : TT - 1;
    int b2 = b + 512;

    const float4* upA = reinterpret_cast<const float4*>(u + ((long long)b  * TT + sc) * NIN);
    const float4* upB = reinterpret_cast<const float4*>(u + ((long long)b2 * TT + sc) * NIN);
    float4 A0 = upA[0], A1 = upA[1];
    float4 B0 = upB[0], B1 = upB[1];
    v2f u0 = {A0.x, B0.x}, u1 = {A0.y, B0.y}, u2 = {A0.z, B0.z}, u3 = {A0.w, B0.w};
    v2f u4 = {A1.x, B1.x}, u5 = {A1.y, B1.y}, u6 = {A1.z, B1.z}, u7 = {A1.w, B1.w};

    v2f d0 = {0.f, 0.f}, d1 = {0.f, 0.f}, d2 = {0.f, 0.f};
    #pragma unroll 8
    for (int j = 0; j < NHI; j++) {
        const float* wj = Wni + j * NIN;        // uniform -> scalar loads
        float bj = bni[j];
        v2f z = {bj, bj};
        z = vfma((v2f){wj[0], wj[0]}, u0, z);
        z = vfma((v2f){wj[1], wj[1]}, u1, z);
        z = vfma((v2f){wj[2], wj[2]}, u2, z);
        z = vfma((v2f){wj[3], wj[3]}, u3, z);
        z = vfma((v2f){wj[4], wj[4]}, u4, z);
        z = vfma((v2f){wj[5], wj[5]}, u5, z);
        z = vfma((v2f){wj[6], wj[6]}, u6, z);
        z = vfma((v2f){wj[7], wj[7]}, u7, z);
        v2f zn;
        zn.x = __shfl_down(z.x, 1);
        zn.y = __shfl_down(z.y, 1);
        v2f dz = zn - z;
        v2f zc  = z  * (v2f){-NL2E, -NL2E};
        v2f dzc = dz * (v2f){-NL2E / 3.0f, -NL2E / 3.0f};
        v2f e0, edz;
        e0.x  = __builtin_amdgcn_exp2f(zc.x);
        e0.y  = __builtin_amdgcn_exp2f(zc.y);
        edz.x = __builtin_amdgcn_exp2f(dzc.x);
        edz.y = __builtin_amdgcn_exp2f(dzc.y);
        v2f e1 = e0 * edz;
        v2f e2 = e1 * edz;
        v2f q0 = e0 + 1.0f, q1 = e1 + 1.0f, q2 = e2 + 1.0f;
        v2f P12 = q1 * q2;
        v2f Dn = q0 * P12;
        v2f rD;
        rD.x = __builtin_amdgcn_rcpf(Dn.x);
        rD.y = __builtin_amdgcn_rcpf(Dn.y);
        v2f P02 = q0 * q2;
        v2f P01 = q0 * q1;
        float wl = Wli[j];
        v2f wr = rD * (v2f){wl, wl};
        d0 = vfma(wr, P12, d0);
        d1 = vfma(wr, P02, d1);
        d2 = vfma(wr, P01, d2);
    }
    float base = tau[0] + bli[0];
    float g0a = DELTA * __builtin_amdgcn_exp2f((base + d0.x) * -NL2E);
    float g1a = DELTA * __builtin_amdgcn_exp2f((base + d1.x) * -NL2E);
    float g2a = DELTA * __builtin_amdgcn_exp2f((base + d2.x) * -NL2E);
    float g0b = DELTA * __builtin_amdgcn_exp2f((base + d0.y) * -NL2E);
    float g1b = DELTA * __builtin_amdgcn_exp2f((base + d1.y) * -NL2E);
    float g2b = DELTA * __builtin_amdgcn_exp2f((base + d2.y) * -NL2E);

    if (s < TT) {
        float* pA = r3 + ((long long)b  * TT + s) * 3;
        float* pB = r3 + ((long long)b2 * TT + s) * 3;
        pA[0] = g0a;
        pB[0] = g0b;
        if (lane < 63 && s < TT - 1) {
            pA[1] = g1a; pA[2] = g2a;
            pB[1] = g1b; pB[2] = g2b;
        }
    }
}

// ---------------- sequential RK4 scan: one b per quad, lane = component -----
// DPP-hazard variant (bit-identical values to r9/r11 scan): permute a = 1+e
// (a VALU result) across the quad, then rcp on the RECEIVING lane. Chain:
// exp2 -> add1 -> dpp(VALU-src) -> rcp -> fma -> fma. Same rcp input bits as
// before -> identical output bits; tests the trans->DPP hazard theory.
__global__ __launch_bounds__(64) void scan_kernel(
    const float* __restrict__ r3, float* __restrict__ xs)
{
    int gt = blockIdx.x * 64 + threadIdx.x;     // 4096 threads
    int b = gt >> 2;
    int l = gt & 3;

    const float4* rp = reinterpret_cast<const float4*>(r3 + (long long)b * TT * 3);
    int comp = (l == 3) ? 1 : l;
    float* xc = xs + (long long)comp * BB * TT + (long long)b * TT;

    bool is2 = (l == 2);
    float cA = is2 ? 40.0f * CS : -2.0f * CS;
    float cB = is2 ? -20.0f * CS : 0.0f;
    float Kl = is2 ? -10.0f * CS : CS;

    float X = (l == 0) ? 0.4736f * CS : (is2 ? 1.8497f * CS : 0.8745f * CS);

#define STEP(G1v, G2v, G3v, G4v) do { \
    float g1 = (G1v), g2 = (G2v), g3 = (G3v); \
    float q  = g1 * (1.0f / 3.0f); \
    float g4_8 = (G4v) * 0.125f; \
    float cA1 = q * cA,    cB1 = q * cB; \
    float cA2 = g2 * cA,   cB2 = g2 * cB; \
    float cA3 = g3 * cA,   cB3 = g3 * cB; \
    float cA4 = g4_8 * cA, cB4 = g4_8 * cB; \
    /* stage 1 */ \
    float e1 = __builtin_amdgcn_exp2f(X); \
    float a1v = 1.0f + e1; \
    float ap11 = qperm<0x89>(a1v), ap21 = qperm<0x10>(a1v); \
    float p11 = __builtin_amdgcn_rcpf(ap11); \
    float p21 = __builtin_amdgcn_rcpf(ap21); \
    float KmX = Kl - X; \
    float pb2 = fmaf(q, KmX, X); \
    float S2 = fmaf(cA1, p11, fmaf(cB1, p21, pb2)); \
    float V1 = fmaf(cA, p11, cB * p21); \
    float W1 = V1 + KmX; \
    /* stage 2 */ \
    float e2 = __builtin_amdgcn_exp2f(S2); \
    float a2v = 1.0f + e2; \
    float ap12 = qperm<0x89>(a2v), ap22 = qperm<0x10>(a2v); \
    float p12 = __builtin_amdgcn_rcpf(ap12); \
    float p22 = __builtin_amdgcn_rcpf(ap22); \
    float KmS2 = Kl - S2; \
    float pb3 = fmaf(g2, KmS2, fmaf(-q, W1, X)); \
    float S3 = fmaf(cA2, p12, fmaf(cB2, p22, pb3)); \
    float V2 = fmaf(cA, p12, cB * p22); \
    float W2 = V2 + KmS2; \
    /* stage 3 */ \
    float e3 = __builtin_amdgcn_exp2f(S3); \
    float a3v = 1.0f + e3; \
    float ap13 = qperm<0x89>(a3v), ap23 = qperm<0x10>(a3v); \
    float p13 = __builtin_amdgcn_rcpf(ap13); \
    float p23 = __builtin_amdgcn_rcpf(ap23); \
    float KmS3 = Kl - S3; \
    float pb4 = fmaf(g3, KmS3, fmaf(-g2, W2, fmaf(g1, W1, X))); \
    float S4 = fmaf(cA3, p13, fmaf(cB3, p23, pb4)); \
    float V3 = fmaf(cA, p13, cB * p23); \
    float W3 = V3 + KmS3; \
    /* stage 4 */ \
    float e4 = __builtin_amdgcn_exp2f(S4); \
    float a4v = 1.0f + e4; \
    float ap14 = qperm<0x89>(a4v), ap24 = qperm<0x10>(a4v); \
    float p14 = __builtin_amdgcn_rcpf(ap14); \
    float p24 = __builtin_amdgcn_rcpf(ap24); \
    float KmS4 = Kl - S4; \
    float t3 = fmaf(3.0f * g3, W3, fmaf(3.0f * g2, W2, g1 * W1)); \
    float pbX = fmaf(g4_8, KmS4, fmaf(0.125f, t3, X)); \
    X = fmaf(cA4, p14, fmaf(cB4, p24, pbX)); \
} while (0)

    float4 f0 = rp[0], f1 = rp[1], f2 = rp[2];
    float4 n0 = rp[3], n1 = rp[4], n2 = rp[5];

    for (int j = 0; j < 510; j++) {
        float4 m0 = rp[3 * j + 6], m1 = rp[3 * j + 7], m2 = rp[3 * j + 8];
        float4 ov;
        ov.x = X;
        STEP(f0.x, f0.y, f0.z, f0.w);  ov.y = X;
        STEP(f0.w, f1.x, f1.y, f1.z);  ov.z = X;
        STEP(f1.z, f1.w, f2.x, f2.y);  ov.w = X;
        *reinterpret_cast<float4*>(xc + 4 * j) = ov;
        STEP(f2.y, f2.z, f2.w, n0.x);
        f0 = n0; f1 = n1; f2 = n2;
        n0 = m0; n1 = m1; n2 = m2;
    }
    {   // chunk 510 (steps 2040..2043)
        float4 ov;
        ov.x = X;
        STEP(f0.x, f0.y, f0.z, f0.w);  ov.y = X;
        STEP(f0.w, f1.x, f1.y, f1.z);  ov.z = X;
        STEP(f1.z, f1.w, f2.x, f2.y);  ov.w = X;
        *reinterpret_cast<float4*>(xc + 4 * 510) = ov;
        STEP(f2.y, f2.z, f2.w, n0.x);
        f0 = n0; f1 = n1; f2 = n2;
    }
    {   // chunk 511 (steps 2044..2046 -> X_2045..X_2047)
        float4 ov;
        ov.x = X;
        STEP(f0.x, f0.y, f0.z, f0.w);  ov.y = X;
        STEP(f0.w, f1.x, f1.y, f1.z);  ov.z = X;
        STEP(f1.z, f1.w, f2.x, f2.y);  ov.w = X;
        *reinterpret_cast<float4*>(xc + 4 * 511) = ov;
    }
#undef STEP
}

// ---------------- readout: out = sigmoid(x @ Wn^T + bn) @ Wl^T + bl --------
// FOUR time points per thread; ONE rcp per (j, 4 points) via product-of-4.
// xs holds X = CS*x, so the sigmoid pre-scale is X * -0.5 (exact).
__global__ __launch_bounds__(256) void out_kernel(
    const float* __restrict__ xs, const float* __restrict__ Wn,
    const float* __restrict__ bn, const float* __restrict__ Wl,
    const float* __restrict__ bl, float* __restrict__ out)
{
    const long long QT = (long long)BB * TT / 4;
    int lt = threadIdx.x;
    long long tid = (long long)blockIdx.x * 256 + lt;   // 0 .. B*T/4-1
    long long t0 = tid, t1 = tid + QT, t2 = tid + 2 * QT, t3i = tid + 3 * QT;
    const float* x1p = xs + (long long)BB * TT;
    const float* x2p = xs + (long long)2 * BB * TT;

    // packed (pt0,pt1) and (pt2,pt3)
    v2f csA0 = { xs[t0],  xs[t1]  }, csB0 = { xs[t2],  xs[t3i]  };
    v2f csA1 = { x1p[t0], x1p[t1] }, csB1 = { x1p[t2], x1p[t3i] };
    v2f csA2 = { x2p[t0], x2p[t1] }, csB2 = { x2p[t2], x2p[t3i] };
    csA0 = csA0 * -0.5f;  csB0 = csB0 * -0.5f;
    csA1 = csA1 * -0.5f;  csB1 = csB1 * -0.5f;
    csA2 = csA2 * -0.5f;  csB2 = csB2 * -0.5f;

    float acc0 = 0.f, acc1 = 0.f, acc2 = 0.f, acc3 = 0.f;
    #pragma unroll 8
    for (int j = 0; j < NHI; j++) {
        float w0 = Wn[3 * j], w1 = Wn[3 * j + 1], w2 = Wn[3 * j + 2];
        float bz = bn[j] * -NL2E;
        v2f zA = vfma((v2f){w0, w0}, csA0,
                 vfma((v2f){w1, w1}, csA1,
                 vfma((v2f){w2, w2}, csA2, (v2f){bz, bz})));
        v2f zB = vfma((v2f){w0, w0}, csB0,
                 vfma((v2f){w1, w1}, csB1,
                 vfma((v2f){w2, w2}, csB2, (v2f){bz, bz})));
        float q0 = 1.0f + __builtin_amdgcn_exp2f(zA.x);
        float q1 = 1.0f + __builtin_amdgcn_exp2f(zA.y);
        float q2 = 1.0f + __builtin_amdgcn_exp2f(zB.x);
        float q3 = 1.0f + __builtin_amdgcn_exp2f(zB.y);
        float p01 = q0 * q1, p23 = q2 * q3;
        float rD = __builtin_amdgcn_rcpf(p01 * p23);
        float wl = Wl[j];
        float w01 = wl * (p23 * rD);     // = wl / (q0*q1)
        float w23 = wl * (p01 * rD);     // = wl / (q2*q3)
        acc0 = fmaf(w01, q1, acc0);      // wl * sig(zA.x) = wl*q1/(q0*q1)... = wl/q0 * q1*... 
        acc1 = fmaf(w01, q0, acc1);
        acc2 = fmaf(w23, q3, acc2);
        acc3 = fmaf(w23, q2, acc3);
    }
    float blv = bl[0];
    out[t0]  = acc0 + blv;
    out[t1]  = acc1 + blv;
    out[t2]  = acc2 + blv;
    out[t3i] = acc3 + blv;
}

extern "C" void kernel_launch(void* const* d_in, const int* in_sizes, int n_in,
                              void* d_out, int out_size, void* d_ws, size_t ws_size,
                              hipStream_t stream) {
    const float* u    = (const float*)d_in[0];
    const float* Wni  = (const float*)d_in[1];
    const float* bni  = (const float*)d_in[2];
    const float* Wli  = (const float*)d_in[3];
    const float* bli  = (const float*)d_in[4];
    const float* tau  = (const float*)d_in[5];
    const float* Wn   = (const float*)d_in[6];
    const float* bn   = (const float*)d_in[7];
    const float* Wl   = (const float*)d_in[8];
    const float* bl   = (const float*)d_in[9];
    float* out = (float*)d_out;

    float* r3 = (float*)d_ws;                          // B*T*3 floats (24 MB)
    float* xs = r3 + (size_t)3 * BB * TT;              // [3][B][T] (24 MB)

    precompute_r<<<(512 * 33) / 4, 256, 0, stream>>>(u, Wni, bni, Wli, bli, tau, r3);
    scan_kernel<<<(BB * 4) / 64, 64, 0, stream>>>(r3, xs);
    out_kernel<<<(BB * TT / 4) / 256, 256, 0, stream>>>(xs, Wn, bn, Wl, bl, out);
}